// Round 3
// baseline (3249.005 us; speedup 1.0000x reference)
//
#include <hip/hip_runtime.h>
#include <hip/hip_cooperative_groups.h>
#include <math.h>

namespace cg = cooperative_groups;

#define IMGD 224
#define HW 50176      // 224*224
#define NK 100
#define NB 8
#define OUT_PER_B 76800   // 100*16*16*3 = 300*256
#define NCHUNK 131        // chunking of 50176: 129x384 + 2x320
#define MSTR 13           // mask/ppk row stride (13 coprime 32: no bank conflicts)
#define GRID_FUSED 528    // 66 chunk-pair columns x 8 images

// R20 (R2) POST-MORTEM: shrinking blocks/dispatch 21.6k->7.8k changed nothing
// => per-WORKGROUP ramp theory dead. Totals track #dispatches x ~12.9us across
// three structurally different rounds => fixed per-dispatch-BOUNDARY cost
// dominates. This round: ONE cooperative kernel, 21 grid.sync()s replace 22
// boundaries. Occupancy-gated with full R2-chain fallback (never fails, at
// worst neutral). All per-chunk/per-row FP op orders verbatim => centers/
// labels/A bit-exact; absmax must stay 0.001953125.

static __device__ __forceinline__ float ratio_f32() {
  return (float)(10.0 / sqrt(224.0 * 224.0 / 100.0));
}

// distance op sequence — the single source of truth for bit-exactness
static __device__ __forceinline__ float dist5s(float f0, float f1, float f2,
                                               float f3, float f4, float fsq,
                                               float c0, float c1, float c2,
                                               float c3, float c4, float q) {
  float dot = __fmul_rn(f0, c0);
  dot = __fmaf_rn(f1, c1, dot);
  dot = __fmaf_rn(f2, c2, dot);
  dot = __fmaf_rn(f3, c3, dot);
  dot = __fmaf_rn(f4, c4, dot);
  return __fsub_rn(__fadd_rn(fsq, q), __fmul_rn(2.0f, dot));
}

static __device__ __forceinline__ float fsq5(float f0, float f1, float f2,
                                             float f3, float f4) {
  float s = __fmul_rn(f0, f0);
  s = __fadd_rn(s, __fmul_rn(f1, f1));
  s = __fadd_rn(s, __fmul_rn(f2, f2));
  s = __fadd_rn(s, __fmul_rn(f3, f3));
  s = __fadd_rn(s, __fmul_rn(f4, f4));
  return s;
}

// ---------------- fused-kernel shared-memory phase union ----------------
struct IterS {
  float4 ck4[NK];
  float4 cval4[2][384];
  float2 ck2[NK];
  unsigned int maskS[2][NK * MSTR];
  float cvalf[2][384];
  int cntS[2][128];
  int offxS[2][128];
  float ubpart[2][12][10];
  float ubg[2][12];
  unsigned int candm[2][12][4];
  int clen[2][12];
  float ared[128];
  unsigned short ppkS[2][NK * MSTR];
  unsigned char clist[2][12][104];
  int wtotS[2];
};                       // ~39.9 KB
struct CombS {
  float st[8 * 6 * NCHUNK];
  float sums[8][6];
  float newc[8][5];
};                       // ~25.5 KB
struct EmbS {
  float Apv[28];
  float Aqw[4][28];
  float sk[4][NK * 3];
};                       // ~5.4 KB
union SmemU { IterS it; CombS cb; EmbS em; };

// ---- A-setup: rows 2b,2b+1 of the resize matrix (bit-exact 128-wide tree) --
static __device__ void a_setup_phase(IterS& S, float* __restrict__ Ag, int b) {
  int tid = threadIdx.x;
  for (int rr = 0; rr < 2; ++rr) {
    int p = 2 * b + rr;
    float cp = (p + 0.5f) * 14.0f - 0.5f;
    if (tid < 128) {
      // level s=128 of the old 256-wide tree: red[t] = tri(t) + tri(t+128)
      float xd0 = fabsf(cp - (float)tid) / 14.0f;
      float trip0 = fmaxf(0.0f, 1.0f - xd0);
      float trip1 = 0.0f;
      int t2 = tid + 128;
      if (t2 < IMGD) {
        float xd = fabsf(cp - (float)t2) / 14.0f;
        trip1 = fmaxf(0.0f, 1.0f - xd);
      }
      S.ared[tid] = trip0 + trip1;
    }
    __syncthreads();
    for (int s = 64; s > 0; s >>= 1) {
      if (tid < s) S.ared[tid] += S.ared[tid + s];
      __syncthreads();
    }
    float Zp = S.ared[0];
    __syncthreads();
    if (tid < IMGD) {
      float xd = fabsf(cp - (float)tid) / 14.0f;
      Ag[p * IMGD + tid] = fmaxf(0.0f, 1.0f - xd) / Zp;
    }
    __syncthreads();
  }
}

// ---- assign: chunk pair (c = 2*bx + half), verbatim R2 iter body ----------
static __device__ void assign_phase(IterS& S, const float* __restrict__ x,
                                    float* __restrict__ centers,
                                    const float* __restrict__ c2g,
                                    float* __restrict__ partials, int flag,
                                    int b, int bx) {
  int tid = threadIdx.x;
  int half = tid >> 7;
  int lt = tid & 127;
  int c = 2 * bx + half;
  int start, len;
  if (c < NCHUNK) {
    start = (c < 129) ? c * 384 : 49536 + (c - 129) * 320;
    len   = (c < 129) ? 384 : 320;
  } else {
    start = 0; len = 0;                 // bx==65 half1: inert chunk
  }

  const float ratio = ratio_f32();
  const float* x0 = x + (size_t)b * 3 * HW;
  if (flag == 0) {
    // self-init: same ops as the original setup => identical center values
    if (tid < NK) {
      int gy = tid / 10, gx = tid - 10 * (tid / 10);
      int cy = (int)((gy + 0.5) * 224.0 / 10.0);  // trunc like .astype(int32)
      int cx = (int)((gx + 0.5) * 224.0 / 10.0);
      int i = cy * IMGD + cx;
      float c0 = x0[i], c1 = x0[HW + i], c2 = x0[2 * HW + i];
      float c3 = __fmul_rn((float)cy, ratio);
      float c4 = __fmul_rn((float)cx, ratio);
      float s = __fmul_rn(c0, c0);
      s = __fadd_rn(s, __fmul_rn(c1, c1));
      s = __fadd_rn(s, __fmul_rn(c2, c2));
      s = __fadd_rn(s, __fmul_rn(c3, c3));
      s = __fadd_rn(s, __fmul_rn(c4, c4));
      S.ck4[tid] = make_float4(c0, c1, c2, c3);
      S.ck2[tid] = make_float2(c4, s);
      if (bx == 0) {   // persist for combine#1's cnt==0 carryover
        float* oc = centers + ((size_t)b * NK + tid) * 5;
        oc[0] = c0; oc[1] = c1; oc[2] = c2; oc[3] = c3; oc[4] = c4;
      }
    }
  } else {
    const float* cb = centers + (size_t)b * NK * 5;
    const float* c2b = c2g + (size_t)b * NK;
    if (tid < NK) {
      S.ck4[tid] = make_float4(cb[tid*5+0], cb[tid*5+1], cb[tid*5+2], cb[tid*5+3]);
      S.ck2[tid] = make_float2(cb[tid*5+4], c2b[tid]);
    }
  }
  for (int t = lt; t < NK * MSTR; t += 128) S.maskS[half][t] = 0u;
  if (lt < 48) S.candm[half][lt >> 2][lt & 3] = 0u;

  // pixel loads early (no LDS dependence) — overlap with pruning phases
  float f0[3], f1[3], f2[3], f3[3], f4[3], fq[3];
  bool vld[3];
  for (int r = 0; r < 3; ++r) {
    int t = lt + r * 128;
    vld[r] = (t < len);
    int i = start + (vld[r] ? t : 0);
    int y = i / IMGD, xw = i - y * IMGD;
    f0[r] = x0[i]; f1[r] = x0[HW + i]; f2[r] = x0[2 * HW + i];
    f3[r] = __fmul_rn((float)y, ratio);
    f4[r] = __fmul_rn((float)xw, ratio);
    fq[r] = fsq5(f0[r], f1[r], f2[r], f3[r], f4[r]);
  }
  __syncthreads();

  // UB phase: thread (g,kb) scans 10 centers; group bounds in-register
  if (lt < 120) {
    int g = lt / 10, kb = lt - 10 * g;
    int i0 = start + g * 32, i1 = i0 + 31;
    int ymin = i0 / IMGD, ymax = i1 / IMGD;
    int cmin = (ymin == ymax) ? (i0 - ymin * IMGD) : 0;
    int cmax = (ymin == ymax) ? (i1 - ymax * IMGD) : (IMGD - 1);
    float f3mn = __fmul_rn((float)ymin, ratio);
    float f3mx = __fmul_rn((float)ymax, ratio);
    float f4mn = __fmul_rn((float)cmin, ratio);
    float f4mx = __fmul_rn((float)cmax, ratio);
    float mn = 3.4e38f;
    for (int k = kb * 10; k < kb * 10 + 10; ++k) {
      float c3 = S.ck4[k].w, c4 = S.ck2[k].x;
      float dy = fmaxf(fabsf(c3 - f3mn), fabsf(c3 - f3mx));
      float dx = fmaxf(fabsf(c4 - f4mn), fabsf(c4 - f4mx));
      mn = fminf(mn, dy * dy + dx * dx + 3.0f);
    }
    S.ubpart[half][g][kb] = mn;
  }
  __syncthreads();
  if (lt < 12) {
    float mn = S.ubpart[half][lt][0];
    for (int j = 1; j < 10; ++j) mn = fminf(mn, S.ubpart[half][lt][j]);
    S.ubg[half][lt] = mn + 1.0f;  // slack >> all f32 rounding at these magnitudes
  }
  __syncthreads();
  if (lt < 120) {
    int g = lt / 10, kb = lt - 10 * g;
    int i0 = start + g * 32, i1 = i0 + 31;
    int ymin = i0 / IMGD, ymax = i1 / IMGD;
    int cmin = (ymin == ymax) ? (i0 - ymin * IMGD) : 0;
    int cmax = (ymin == ymax) ? (i1 - ymax * IMGD) : (IMGD - 1);
    float f3mn = __fmul_rn((float)ymin, ratio);
    float f3mx = __fmul_rn((float)ymax, ratio);
    float f4mn = __fmul_rn((float)cmin, ratio);
    float f4mx = __fmul_rn((float)cmax, ratio);
    float lim = S.ubg[half][g];
    for (int k = kb * 10; k < kb * 10 + 10; ++k) {
      float c3 = S.ck4[k].w, c4 = S.ck2[k].x;
      float dy = fmaxf(0.0f, fmaxf(f3mn - c3, c3 - f3mx));
      float dx = fmaxf(0.0f, fmaxf(f4mn - c4, c4 - f4mx));
      if (dy * dy + dx * dx <= lim)
        atomicOr(&S.candm[half][g][k >> 5], 1u << (k & 31));
    }
  }
  __syncthreads();
  // dense ascending-k candidate lists
  if (lt < 12) {
    int len2 = 0;
    for (int w = 0; w < 4; ++w) {
      unsigned int m = S.candm[half][lt][w];
      while (m) {
        int j = __ffs(m) - 1;
        m &= m - 1;
        S.clist[half][lt][len2++] = (unsigned char)(w * 32 + j);
      }
    }
    S.clen[half][lt] = len2;
  }
  __syncthreads();

  // pruned distance loop: candidates ascending k (first-index ties safe)
  float best[3]; int bk[3];
  for (int r = 0; r < 3; ++r) {
    best[r] = 3.4e38f; bk[r] = 0;
    int t = lt + r * 128;
    int g = (t < 384) ? (t >> 5) : 0;
    int n = S.clen[half][g];
    for (int j = 0; j < n; ++j) {
      int k = S.clist[half][g][j];
      float4 a4 = S.ck4[k];
      float2 a2 = S.ck2[k];
      float d = dist5s(f0[r], f1[r], f2[r], f3[r], f4[r], fq[r],
                       a4.x, a4.y, a4.z, a4.w, a2.x, a2.y);
      if (d < best[r]) { best[r] = d; bk[r] = k; }
    }
  }
  for (int r = 0; r < 3; ++r) {
    int t = lt + r * 128;
    if (vld[r]) atomicOr(&S.maskS[half][bk[r] * MSTR + (t >> 5)], 1u << (t & 31));
  }
  __syncthreads();

  // per-k cumulative popcounts (stride-13 rows: conflict-free)
  int myCnt = 0;
  if (lt < NK) {
    int s = 0;
    for (int g = 0; g < 12; ++g) {
      S.ppkS[half][lt * MSTR + g] = (unsigned short)s;
      s += __popc(S.maskS[half][lt * MSTR + g]);
    }
    myCnt = s;
  }
  S.cntS[half][lt] = myCnt;
  __syncthreads();

  // inclusive prefix over 128 counts per half: shfl per wave + cross-wave fixup
  int v = myCnt;
  for (int d = 1; d < 64; d <<= 1) {
    int u = __shfl_up(v, d, 64);
    if ((tid & 63) >= d) v += u;
  }
  if (lt == 63) S.wtotS[half] = v;
  __syncthreads();
  if (lt >= 64) v += S.wtotS[half];
  S.offxS[half][lt] = v;
  __syncthreads();

  // stable VALUE scatter: pos = (off[k]-cnt[k]) + rank_within_k(t)
  for (int r = 0; r < 3; ++r) {
    int t = lt + r * 128;
    if (vld[r]) {
      int g = t >> 5, j = t & 31;
      unsigned int m = S.maskS[half][bk[r] * MSTR + g];
      int rank = S.ppkS[half][bk[r] * MSTR + g] + __popc(m & ((1u << j) - 1u));
      int pos = S.offxS[half][bk[r]] - S.cntS[half][bk[r]] + rank;
      S.cval4[half][pos] = make_float4(f0[r], f1[r], f2[r], f3[r]);
      S.cvalf[half][pos] = f4[r];
    }
  }
  __syncthreads();

  // scan: thread k walks its consecutive compacted range (ascending t)
  if (c < NCHUNK && lt < NK) {
    int n = S.cntS[half][lt];
    int base = S.offxS[half][lt] - n;
    float s0 = 0.f, s1 = 0.f, s2 = 0.f, s3 = 0.f, s4 = 0.f, s5 = 0.f;
    for (int m = 0; m < n; ++m) {
      float4 vv = S.cval4[half][base + m];
      float ww = S.cvalf[half][base + m];
      s0 = __fadd_rn(s0, vv.x);
      s1 = __fadd_rn(s1, vv.y);
      s2 = __fadd_rn(s2, vv.z);
      s3 = __fadd_rn(s3, vv.w);
      s4 = __fadd_rn(s4, ww);
      s5 += 1.0f;
    }
    // k-major layout [b][k][j][c]: combine reads contiguous
    float* pp = partials + ((size_t)(b * NK + lt) * 6) * NCHUNK + c;
    pp[0 * NCHUNK] = s0; pp[1 * NCHUNK] = s1; pp[2 * NCHUNK] = s2;
    pp[3 * NCHUNK] = s3; pp[4 * NCHUNK] = s4; pp[5 * NCHUNK] = s5;
  }
  __syncthreads();
}

// ---- combine: 8 bk-rows; per-row op order identical => bit-exact ----------
static __device__ void combine_phase(CombS& S, float* __restrict__ centers,
                                     const float* __restrict__ partials,
                                     float* __restrict__ c2g, int bb) {
  int tid = threadIdx.x;
  const float* base = partials + (size_t)bb * 8 * 6 * NCHUNK;
  for (int t = tid; t < 8 * 6 * NCHUNK; t += 256) S.st[t] = base[t];
  __syncthreads();
  if (tid < 48) {
    int row = tid / 6, comp = tid - 6 * (tid / 6);
    const float* rp = S.st + (row * 6 + comp) * NCHUNK;
    float s = rp[0];                   // C = 0 + chunk0 (exact)
    for (int c = 1; c < NCHUNK; ++c) s = __fadd_rn(s, rp[c]);
    S.sums[row][comp] = s;
  }
  __syncthreads();
  if (tid < 40) {
    int row = tid / 5, d = tid - 5 * (tid / 5);
    float cntv = S.sums[row][5];
    float* cc = centers + (size_t)(bb * 8 + row) * 5;
    float v;
    if (cntv > 0.0f) {                 // where(cnt>0, new, centers)
      float m = fmaxf(cntv, 1.0f);     // np.maximum(cnt,1.0): exact int in f32
      v = __fdiv_rn(S.sums[row][d], m);
      cc[d] = v;
    } else {
      v = cc[d];                       // unchanged center
    }
    S.newc[row][d] = v;
  }
  __syncthreads();
  if (tid < 8) {
    // c2 = sum(centers*centers): rounded products, sequential adds
    float t0 = __fmul_rn(S.newc[tid][0], S.newc[tid][0]);
    t0 = __fadd_rn(t0, __fmul_rn(S.newc[tid][1], S.newc[tid][1]));
    t0 = __fadd_rn(t0, __fmul_rn(S.newc[tid][2], S.newc[tid][2]));
    t0 = __fadd_rn(t0, __fmul_rn(S.newc[tid][3], S.newc[tid][3]));
    t0 = __fadd_rn(t0, __fmul_rn(S.newc[tid][4], S.newc[tid][4]));
    c2g[bb * 8 + tid] = t0;
  }
  __syncthreads();
}

// ---- labels: final assignment (chunk pair per block), bit-exact argmin ----
static __device__ void label_phase(IterS& S, const float* __restrict__ x,
                                   const float* __restrict__ centers,
                                   const float* __restrict__ c2g,
                                   unsigned char* __restrict__ labels,
                                   int b, int bx) {
  int tid = threadIdx.x;
  int half = tid >> 7;
  int lt = tid & 127;
  int c = 2 * bx + half;
  int start, len;
  if (c < NCHUNK) {
    start = (c < 129) ? c * 384 : 49536 + (c - 129) * 320;
    len   = (c < 129) ? 384 : 320;
  } else {
    start = 0; len = 0;
  }

  const float ratio = ratio_f32();
  const float* x0 = x + (size_t)b * 3 * HW;
  const float* cb = centers + (size_t)b * NK * 5;
  const float* c2b = c2g + (size_t)b * NK;
  if (tid < NK) {
    S.ck4[tid] = make_float4(cb[tid*5+0], cb[tid*5+1], cb[tid*5+2], cb[tid*5+3]);
    S.ck2[tid] = make_float2(cb[tid*5+4], c2b[tid]);
  }
  if (lt < 48) S.candm[half][lt >> 2][lt & 3] = 0u;

  float f0[3], f1[3], f2[3], f3[3], f4[3], fq[3];
  int ii[3];
  bool vld[3];
  for (int r = 0; r < 3; ++r) {
    int t = lt + r * 128;
    vld[r] = (t < len);
    int i = start + (vld[r] ? t : 0);
    ii[r] = i;
    int y = i / IMGD, xw = i - y * IMGD;
    f0[r] = x0[i]; f1[r] = x0[HW + i]; f2[r] = x0[2 * HW + i];
    f3[r] = __fmul_rn((float)y, ratio);
    f4[r] = __fmul_rn((float)xw, ratio);
    fq[r] = fsq5(f0[r], f1[r], f2[r], f3[r], f4[r]);
  }
  __syncthreads();

  if (lt < 120) {
    int g = lt / 10, kb = lt - 10 * g;
    int i0 = start + g * 32, i1 = i0 + 31;
    int ymin = i0 / IMGD, ymax = i1 / IMGD;
    int cmin = (ymin == ymax) ? (i0 - ymin * IMGD) : 0;
    int cmax = (ymin == ymax) ? (i1 - ymax * IMGD) : (IMGD - 1);
    float f3mn = __fmul_rn((float)ymin, ratio);
    float f3mx = __fmul_rn((float)ymax, ratio);
    float f4mn = __fmul_rn((float)cmin, ratio);
    float f4mx = __fmul_rn((float)cmax, ratio);
    float mn = 3.4e38f;
    for (int k = kb * 10; k < kb * 10 + 10; ++k) {
      float c3 = S.ck4[k].w, c4 = S.ck2[k].x;
      float dy = fmaxf(fabsf(c3 - f3mn), fabsf(c3 - f3mx));
      float dx = fmaxf(fabsf(c4 - f4mn), fabsf(c4 - f4mx));
      mn = fminf(mn, dy * dy + dx * dx + 3.0f);
    }
    S.ubpart[half][g][kb] = mn;
  }
  __syncthreads();
  if (lt < 12) {
    float mn = S.ubpart[half][lt][0];
    for (int j = 1; j < 10; ++j) mn = fminf(mn, S.ubpart[half][lt][j]);
    S.ubg[half][lt] = mn + 1.0f;
  }
  __syncthreads();
  if (lt < 120) {
    int g = lt / 10, kb = lt - 10 * g;
    int i0 = start + g * 32, i1 = i0 + 31;
    int ymin = i0 / IMGD, ymax = i1 / IMGD;
    int cmin = (ymin == ymax) ? (i0 - ymin * IMGD) : 0;
    int cmax = (ymin == ymax) ? (i1 - ymax * IMGD) : (IMGD - 1);
    float f3mn = __fmul_rn((float)ymin, ratio);
    float f3mx = __fmul_rn((float)ymax, ratio);
    float f4mn = __fmul_rn((float)cmin, ratio);
    float f4mx = __fmul_rn((float)cmax, ratio);
    float lim = S.ubg[half][g];
    for (int k = kb * 10; k < kb * 10 + 10; ++k) {
      float c3 = S.ck4[k].w, c4 = S.ck2[k].x;
      float dy = fmaxf(0.0f, fmaxf(f3mn - c3, c3 - f3mx));
      float dx = fmaxf(0.0f, fmaxf(f4mn - c4, c4 - f4mx));
      if (dy * dy + dx * dx <= lim)
        atomicOr(&S.candm[half][g][k >> 5], 1u << (k & 31));
    }
  }
  __syncthreads();

  // pruned distance loop over candm words: k ascending (w asc, ffs asc) —
  // identical candidate sequence to the dense-list version.
  float best[3]; int bk[3];
  for (int r = 0; r < 3; ++r) {
    best[r] = 3.4e38f; bk[r] = 0;
    int t = lt + r * 128;
    int g = (t < 384) ? (t >> 5) : 0;
    for (int w = 0; w < 4; ++w) {
      unsigned int m = S.candm[half][g][w];
      while (m) {
        int j = __ffs(m) - 1;
        m &= m - 1;
        int k = (w << 5) + j;
        float4 a4 = S.ck4[k];
        float2 a2 = S.ck2[k];
        float d = dist5s(f0[r], f1[r], f2[r], f3[r], f4[r], fq[r],
                         a4.x, a4.y, a4.z, a4.w, a2.x, a2.y);
        if (d < best[r]) { best[r] = d; bk[r] = k; }
      }
    }
  }
  unsigned char* lb = labels + (size_t)b * HW;
  for (int r = 0; r < 3; ++r)
    if (vld[r]) lb[ii[r]] = (unsigned char)bk[r];
  __syncthreads();
}

// ---- embed: 4 q-windows sharing the p-row strip; labels + A precomputed ---
static __device__ void embed_phase(EmbS& S, const float* __restrict__ x,
                                   const unsigned char* __restrict__ labels,
                                   const float* __restrict__ Ag,
                                   float* __restrict__ out, int b, int p,
                                   int qg) {
  int q0 = qg * 4;
  int tid = threadIdx.x;

  int h0 = max(0, 14 * p - 7), h1 = min(IMGD - 1, 14 * p + 20);
  int hl = h1 - h0 + 1;
  int w0q[4], w1q[4];
#pragma unroll
  for (int qi = 0; qi < 4; ++qi) {
    int q = q0 + qi;
    w0q[qi] = max(0, 14 * q - 7);
    w1q[qi] = min(IMGD - 1, 14 * q + 20);
  }
  int W0 = w0q[0], W1 = w1q[3];
  int WU = W1 - W0 + 1;

  if (tid < hl) S.Apv[tid] = Ag[p * IMGD + h0 + tid];
  {
    int t = tid - 64;
    if (t >= 0 && t < 112) {
      int qi = t / 28, dw = t - 28 * qi;
      if (dw <= w1q[qi] - w0q[qi])
        S.Aqw[qi][dw] = Ag[(q0 + qi) * IMGD + w0q[qi] + dw];
    }
  }
  for (int t = tid; t < 4 * NK * 3; t += 256)
    S.sk[t / (NK * 3)][t % (NK * 3)] = 0.0f;
  __syncthreads();

  const float* xb = x + (size_t)b * 3 * HW;
  const unsigned char* lb = labels + (size_t)b * HW;
  int n = hl * WU;                    // <= 28*70 = 1960 <= 8*256
  for (int r = 0; r < 8; ++r) {
    int idx = tid + r * 256;
    if (idx >= n) break;
    int dh = idx / WU;
    int dcol = idx - dh * WU;
    int col = W0 + dcol;
    int i = (h0 + dh) * IMGD + col;
    float v0 = xb[i], v1 = xb[HW + i], v2 = xb[2 * HW + i];
    int k = lb[i];
    float ap = S.Apv[dh];
#pragma unroll
    for (int qi = 0; qi < 4; ++qi) {
      if (col >= w0q[qi] && col <= w1q[qi]) {
        float wgt = ap * S.Aqw[qi][col - w0q[qi]];
        atomicAdd(&S.sk[qi][k * 3 + 0], wgt * v0);
        atomicAdd(&S.sk[qi][k * 3 + 1], wgt * v1);
        atomicAdd(&S.sk[qi][k * 3 + 2], wgt * v2);
      }
    }
  }
  __syncthreads();

  float* outb = out + (size_t)b * OUT_PER_B;
  for (int t = tid; t < 4 * NK * 3; t += 256) {
    int qi = t / (NK * 3), t3 = t - qi * (NK * 3);
    int k = t3 / 3, cc = t3 - 3 * k;
    int base = p * 48 + (q0 + qi) * 3;
    int f = k * 768 + base + cc;              // flat [K,P,P,C] index
    outb[(f & 255) * 300 + (f >> 8)] = S.sk[qi][t3]; // view(B,300,256)+transpose
  }
}

// ---------------- the fused cooperative kernel: 1 dispatch, 21 gsyncs ------
__global__ void __launch_bounds__(256, 3) fused_kernel(
    const float* __restrict__ x, float* __restrict__ centers,
    float* __restrict__ c2g, float* __restrict__ partials,
    float* __restrict__ Ag, unsigned char* __restrict__ labels,
    float* __restrict__ out) {
  __shared__ SmemU sm;
  cg::grid_group grid = cg::this_grid();
  int bid = blockIdx.x;
  int b = bid / 66, bx = bid - 66 * b;

  if (bx == 65) a_setup_phase(sm.it, Ag, b);   // block-local barriers only

  assign_phase(sm.it, x, centers, c2g, partials, 0, b, bx);
  __threadfence(); grid.sync(); __threadfence();
  if (bid < 100) combine_phase(sm.cb, centers, partials, c2g, bid);
  __threadfence(); grid.sync(); __threadfence();
  for (int it = 1; it < 10; ++it) {
    assign_phase(sm.it, x, centers, c2g, partials, 1, b, bx);
    __threadfence(); grid.sync(); __threadfence();
    if (bid < 100) combine_phase(sm.cb, centers, partials, c2g, bid);
    __threadfence(); grid.sync(); __threadfence();
  }
  label_phase(sm.it, x, centers, c2g, labels, b, bx);
  __threadfence(); grid.sync(); __threadfence();
  if (bid < 512) {
    int inner = bid & 63;
    embed_phase(sm.em, x, labels, Ag, out, bid >> 6, inner >> 2, inner & 3);
  }
}

// ======================= fallback: the R2 dispatch chain ====================
__global__ void __launch_bounds__(256, 2) iter_kernel(
    const float* __restrict__ x, float* __restrict__ centers,
    const float* __restrict__ c2g, float* __restrict__ partials, int flag,
    float* __restrict__ Ag) {
  __shared__ SmemU sm;
  int bx = blockIdx.x, b = blockIdx.y;
  if (bx >= 66) { a_setup_phase(sm.it, Ag, b); return; }
  assign_phase(sm.it, x, centers, c2g, partials, flag, b, bx);
}

__global__ void __launch_bounds__(256) combine_update_kernel(
    float* __restrict__ centers, const float* __restrict__ partials,
    float* __restrict__ c2g) {
  __shared__ SmemU sm;
  combine_phase(sm.cb, centers, partials, c2g, blockIdx.x);
}

__global__ void __launch_bounds__(256) label_only_kernel(
    const float* __restrict__ x, const float* __restrict__ centers,
    const float* __restrict__ c2g, unsigned char* __restrict__ labels) {
  __shared__ SmemU sm;
  label_phase(sm.it, x, centers, c2g, labels, blockIdx.y, blockIdx.x);
}

__global__ void __launch_bounds__(256) embed_kernel(
    const float* __restrict__ x, const unsigned char* __restrict__ labels,
    const float* __restrict__ Ag, float* __restrict__ out) {
  __shared__ SmemU sm;
  embed_phase(sm.em, x, labels, Ag, out, blockIdx.y, blockIdx.x >> 2,
              blockIdx.x & 3);
}

extern "C" void kernel_launch(void* const* d_in, const int* in_sizes, int n_in,
                              void* d_out, int out_size, void* d_ws, size_t ws_size,
                              hipStream_t stream) {
  const float* x = (const float*)d_in[0];
  float* out = (float*)d_out;
  char* ws = (char*)d_ws;
  // ws layout:
  float* centers        = (float*)(ws + 16384);      // 16000 B
  float* c2g            = (float*)(ws + 49152);      // 3200 B
  float* Ag             = (float*)(ws + 65536);      // 16*224*4 = 14336 B
  unsigned char* labels = (unsigned char*)(ws + 98304); // 8*50176 = 401408 B
  float* partials       = (float*)(ws + 1703936);    // 8*100*6*131*4 = 2515200 B

  // one-time capability check: can 528 blocks be co-resident (cooperative)?
  static int coop_ok = -1;
  if (coop_ok < 0) {
    int maxB = 0, nCU = 0;
    hipError_t e1 = hipOccupancyMaxActiveBlocksPerMultiprocessor(
        &maxB, fused_kernel, 256, 0);
    hipError_t e2 = hipDeviceGetAttribute(
        &nCU, hipDeviceAttributeMultiprocessorCount, 0);
    coop_ok = (e1 == hipSuccess && e2 == hipSuccess &&
               (long)maxB * nCU >= GRID_FUSED) ? 1 : 0;
    (void)hipGetLastError();
  }

  bool done = false;
  if (coop_ok == 1) {
    void* args[] = {(void*)&x,       (void*)&centers, (void*)&c2g,
                    (void*)&partials, (void*)&Ag,      (void*)&labels,
                    (void*)&out};
    hipError_t e = hipLaunchCooperativeKernel(
        (const void*)fused_kernel, dim3(GRID_FUSED), dim3(256), args, 0,
        stream);
    if (e == hipSuccess) {
      done = true;
    } else {
      (void)hipGetLastError();   // clear error state; fall back permanently
      coop_ok = 0;
    }
  }
  if (!done) {
    dim3 ig0(67, NB);             // bx 0..65: chunk pairs; bx 66: A-setup
    dim3 ig(66, NB);
    iter_kernel<<<ig0, 256, 0, stream>>>(x, centers, c2g, partials, 0, Ag);
    combine_update_kernel<<<NB * NK / 8, 256, 0, stream>>>(centers, partials, c2g);
    for (int it = 1; it < 10; ++it) {
      iter_kernel<<<ig, 256, 0, stream>>>(x, centers, c2g, partials, 1, Ag);
      combine_update_kernel<<<NB * NK / 8, 256, 0, stream>>>(centers, partials, c2g);
    }
    label_only_kernel<<<dim3(66, NB), 256, 0, stream>>>(x, centers, c2g, labels);
    dim3 egrid(64, NB);
    embed_kernel<<<egrid, 256, 0, stream>>>(x, labels, Ag, out);
  }
}

// Round 4
// 308.919 us; speedup vs baseline: 10.5173x; 10.5173x over previous
//
#include <hip/hip_runtime.h>
#include <math.h>

#define IMGD 224
#define HW 50176      // 224*224
#define NK 100
#define NB 8
#define OUT_PER_B 76800   // 100*16*16*3 = 300*256
#define NCHUNK 131        // chunking of 50176: 129x384 + 2x320
#define MSTR 13           // mask/ppk row stride (13 coprime 32: no bank conflicts)

// R12/R14/R18 (prior session) + R3 (this session): cross-block coherence
// INSIDE a kernel is unaffordable on gfx950 in EVERY form measured —
// per-block fence ~1.5us serialized, grid.sync() ~146us each (8-XCD L2
// writeback/invalidate). The kernel boundary is the only cheap coherence
// point. Chain depth (assign->combine x10) is irreducible; this round removes
// the label dispatch instead: embed blocks label their own strip via the
// box-pruning bound (proven exact, ascending-k => labels bit-identical).
// 23 -> 21 dispatches.

static __device__ __forceinline__ float ratio_f32() {
  return (float)(10.0 / sqrt(224.0 * 224.0 / 100.0));
}

// distance op sequence — the single source of truth for bit-exactness
static __device__ __forceinline__ float dist5s(float f0, float f1, float f2,
                                               float f3, float f4, float fsq,
                                               float c0, float c1, float c2,
                                               float c3, float c4, float q) {
  float dot = __fmul_rn(f0, c0);
  dot = __fmaf_rn(f1, c1, dot);
  dot = __fmaf_rn(f2, c2, dot);
  dot = __fmaf_rn(f3, c3, dot);
  dot = __fmaf_rn(f4, c4, dot);
  return __fsub_rn(__fadd_rn(fsq, q), __fmul_rn(2.0f, dot));
}

static __device__ __forceinline__ float fsq5(float f0, float f1, float f2,
                                             float f3, float f4) {
  float s = __fmul_rn(f0, f0);
  s = __fadd_rn(s, __fmul_rn(f1, f1));
  s = __fadd_rn(s, __fmul_rn(f2, f2));
  s = __fadd_rn(s, __fmul_rn(f3, f3));
  s = __fadd_rn(s, __fmul_rn(f4, f4));
  return s;
}

// ---------- fused assign+partial: 2 chunks per 256-thread block ----------
// half = tid>>7 picks chunk c = 2*bx + half; lt = tid&127 runs the per-chunk
// code with chunk-local LDS indexed [half]. Centers shared (same b).
// bx==66 blocks (flag==0 grid only) materialize resize-matrix rows 2b,2b+1
// into Ag (identical 128-wide tree pairing => A bit-identical).
// Pruning: UB = min_k(dy_max^2+dx_max^2+3), keep k iff dy_min^2+dx_min^2 <=
// UB+1.0 (slack >> f32 rounding); candidates walked ascending-k straight out
// of the candm bitmask => argmin + first-index ties bit-preserved.
__global__ void __launch_bounds__(256, 2) iter_kernel(
    const float* __restrict__ x, float* __restrict__ centers,
    const float* __restrict__ c2g, float* __restrict__ partials, int flag,
    float* __restrict__ Ag) {
  __shared__ float4 ck4[NK];
  __shared__ float2 ck2[NK];
  __shared__ unsigned int maskS[2][NK * MSTR];
  __shared__ unsigned short ppkS[2][NK * MSTR];
  __shared__ float4 cval4[2][384];
  __shared__ float  cvalf[2][384];
  __shared__ int cntS[2][128];
  __shared__ int offxS[2][128];
  __shared__ int wtotS[2];
  __shared__ float ubpart[2][12][10];
  __shared__ float ubg[2][12];
  __shared__ unsigned int candm[2][12][4];
  __shared__ float ared[128];
  int bx = blockIdx.x, b = blockIdx.y;
  int tid = threadIdx.x;

  if (bx >= 66) {
    // ---- A-setup block (present only in the flag==0 dispatch) ----
    for (int rr = 0; rr < 2; ++rr) {
      int p = 2 * b + rr;
      float cp = (p + 0.5f) * 14.0f - 0.5f;
      if (tid < 128) {
        // level s=128 of the old 256-wide tree: red[t] = tri(t) + tri(t+128)
        float xd0 = fabsf(cp - (float)tid) / 14.0f;
        float trip0 = fmaxf(0.0f, 1.0f - xd0);
        float trip1 = 0.0f;
        int t2 = tid + 128;
        if (t2 < IMGD) {
          float xd = fabsf(cp - (float)t2) / 14.0f;
          trip1 = fmaxf(0.0f, 1.0f - xd);
        }
        ared[tid] = trip0 + trip1;
      }
      __syncthreads();
      for (int s = 64; s > 0; s >>= 1) {
        if (tid < s) ared[tid] += ared[tid + s];
        __syncthreads();
      }
      float Zp = ared[0];
      __syncthreads();
      if (tid < IMGD) {
        float xd = fabsf(cp - (float)tid) / 14.0f;
        Ag[p * IMGD + tid] = fmaxf(0.0f, 1.0f - xd) / Zp;  // same expr as before
      }
      __syncthreads();
    }
    return;
  }

  int half = tid >> 7;
  int lt = tid & 127;
  int c = 2 * bx + half;
  int start, len;
  if (c < NCHUNK) {
    start = (c < 129) ? c * 384 : 49536 + (c - 129) * 320;
    len   = (c < 129) ? 384 : 320;
  } else {
    start = 0; len = 0;                 // bx==65 half1: inert chunk
  }

  const float ratio = ratio_f32();
  const float* x0 = x + (size_t)b * 3 * HW;
  if (flag == 0) {
    // self-init: same ops as the original setup => identical center values
    if (tid < NK) {
      int gy = tid / 10, gx = tid - 10 * (tid / 10);
      int cy = (int)((gy + 0.5) * 224.0 / 10.0);  // trunc like .astype(int32)
      int cx = (int)((gx + 0.5) * 224.0 / 10.0);
      int i = cy * IMGD + cx;
      float c0 = x0[i], c1 = x0[HW + i], c2 = x0[2 * HW + i];
      float c3 = __fmul_rn((float)cy, ratio);
      float c4 = __fmul_rn((float)cx, ratio);
      float s = __fmul_rn(c0, c0);
      s = __fadd_rn(s, __fmul_rn(c1, c1));
      s = __fadd_rn(s, __fmul_rn(c2, c2));
      s = __fadd_rn(s, __fmul_rn(c3, c3));
      s = __fadd_rn(s, __fmul_rn(c4, c4));
      ck4[tid] = make_float4(c0, c1, c2, c3);
      ck2[tid] = make_float2(c4, s);
      if (bx == 0) {   // persist for combine#1's cnt==0 carryover
        float* oc = centers + ((size_t)b * NK + tid) * 5;
        oc[0] = c0; oc[1] = c1; oc[2] = c2; oc[3] = c3; oc[4] = c4;
      }
    }
  } else {
    const float* cb = centers + (size_t)b * NK * 5;
    const float* c2b = c2g + (size_t)b * NK;
    if (tid < NK) {
      ck4[tid] = make_float4(cb[tid*5+0], cb[tid*5+1], cb[tid*5+2], cb[tid*5+3]);
      ck2[tid] = make_float2(cb[tid*5+4], c2b[tid]);
    }
  }
  for (int t = lt; t < NK * MSTR; t += 128) maskS[half][t] = 0u;
  if (lt < 48) candm[half][lt >> 2][lt & 3] = 0u;

  // pixel loads early (no LDS dependence) — overlap with pruning phases
  float f0[3], f1[3], f2[3], f3[3], f4[3], fq[3];
  bool vld[3];
  for (int r = 0; r < 3; ++r) {
    int t = lt + r * 128;
    vld[r] = (t < len);
    int i = start + (vld[r] ? t : 0);
    int y = i / IMGD, xw = i - y * IMGD;
    f0[r] = x0[i]; f1[r] = x0[HW + i]; f2[r] = x0[2 * HW + i];
    f3[r] = __fmul_rn((float)y, ratio);
    f4[r] = __fmul_rn((float)xw, ratio);
    fq[r] = fsq5(f0[r], f1[r], f2[r], f3[r], f4[r]);
  }
  __syncthreads();

  // UB phase: thread (g,kb) scans 10 centers; group bounds in-register
  if (lt < 120) {
    int g = lt / 10, kb = lt - 10 * g;
    int i0 = start + g * 32, i1 = i0 + 31;
    int ymin = i0 / IMGD, ymax = i1 / IMGD;
    int cmin = (ymin == ymax) ? (i0 - ymin * IMGD) : 0;
    int cmax = (ymin == ymax) ? (i1 - ymax * IMGD) : (IMGD - 1);
    float f3mn = __fmul_rn((float)ymin, ratio);
    float f3mx = __fmul_rn((float)ymax, ratio);
    float f4mn = __fmul_rn((float)cmin, ratio);
    float f4mx = __fmul_rn((float)cmax, ratio);
    float mn = 3.4e38f;
    for (int k = kb * 10; k < kb * 10 + 10; ++k) {
      float c3 = ck4[k].w, c4 = ck2[k].x;
      float dy = fmaxf(fabsf(c3 - f3mn), fabsf(c3 - f3mx));
      float dx = fmaxf(fabsf(c4 - f4mn), fabsf(c4 - f4mx));
      mn = fminf(mn, dy * dy + dx * dx + 3.0f);
    }
    ubpart[half][g][kb] = mn;
  }
  __syncthreads();
  if (lt < 12) {
    float mn = ubpart[half][lt][0];
    for (int j = 1; j < 10; ++j) mn = fminf(mn, ubpart[half][lt][j]);
    ubg[half][lt] = mn + 1.0f;  // slack >> all f32 rounding at these magnitudes
  }
  __syncthreads();
  if (lt < 120) {
    int g = lt / 10, kb = lt - 10 * g;
    int i0 = start + g * 32, i1 = i0 + 31;
    int ymin = i0 / IMGD, ymax = i1 / IMGD;
    int cmin = (ymin == ymax) ? (i0 - ymin * IMGD) : 0;
    int cmax = (ymin == ymax) ? (i1 - ymax * IMGD) : (IMGD - 1);
    float f3mn = __fmul_rn((float)ymin, ratio);
    float f3mx = __fmul_rn((float)ymax, ratio);
    float f4mn = __fmul_rn((float)cmin, ratio);
    float f4mx = __fmul_rn((float)cmax, ratio);
    float lim = ubg[half][g];
    for (int k = kb * 10; k < kb * 10 + 10; ++k) {
      float c3 = ck4[k].w, c4 = ck2[k].x;
      float dy = fmaxf(0.0f, fmaxf(f3mn - c3, c3 - f3mx));
      float dx = fmaxf(0.0f, fmaxf(f4mn - c4, c4 - f4mx));
      if (dy * dy + dx * dx <= lim)
        atomicOr(&candm[half][g][k >> 5], 1u << (k & 31));
    }
  }
  __syncthreads();

  // pruned distance loop straight off the candm bitmask: k ascending
  // (w asc, ffs asc) — identical candidate sequence to the dense-list
  // version; first-index ties preserved. (clist build phase removed.)
  float best[3]; int bk[3];
  for (int r = 0; r < 3; ++r) {
    best[r] = 3.4e38f; bk[r] = 0;
    int t = lt + r * 128;
    int g = (t < 384) ? (t >> 5) : 0;
    for (int w = 0; w < 4; ++w) {
      unsigned int m = candm[half][g][w];
      while (m) {
        int j = __ffs(m) - 1;
        m &= m - 1;
        int k = (w << 5) + j;
        float4 a4 = ck4[k];
        float2 a2 = ck2[k];
        float d = dist5s(f0[r], f1[r], f2[r], f3[r], f4[r], fq[r],
                         a4.x, a4.y, a4.z, a4.w, a2.x, a2.y);
        if (d < best[r]) { best[r] = d; bk[r] = k; }
      }
    }
  }
  for (int r = 0; r < 3; ++r) {
    int t = lt + r * 128;
    if (vld[r]) atomicOr(&maskS[half][bk[r] * MSTR + (t >> 5)], 1u << (t & 31));
  }
  __syncthreads();

  // per-k cumulative popcounts (stride-13 rows: conflict-free)
  int myCnt = 0;
  if (lt < NK) {
    int s = 0;
    for (int g = 0; g < 12; ++g) {
      ppkS[half][lt * MSTR + g] = (unsigned short)s;
      s += __popc(maskS[half][lt * MSTR + g]);
    }
    myCnt = s;
  }
  cntS[half][lt] = myCnt;
  __syncthreads();

  // inclusive prefix over 128 counts per half: shfl per wave + cross-wave fixup
  int v = myCnt;
  for (int d = 1; d < 64; d <<= 1) {
    int u = __shfl_up(v, d, 64);
    if ((tid & 63) >= d) v += u;
  }
  if (lt == 63) wtotS[half] = v;
  __syncthreads();
  if (lt >= 64) v += wtotS[half];
  offxS[half][lt] = v;
  __syncthreads();

  // stable VALUE scatter: pos = (off[k]-cnt[k]) + rank_within_k(t)
  for (int r = 0; r < 3; ++r) {
    int t = lt + r * 128;
    if (vld[r]) {
      int g = t >> 5, j = t & 31;
      unsigned int m = maskS[half][bk[r] * MSTR + g];
      int rank = ppkS[half][bk[r] * MSTR + g] + __popc(m & ((1u << j) - 1u));
      int pos = offxS[half][bk[r]] - cntS[half][bk[r]] + rank;
      cval4[half][pos] = make_float4(f0[r], f1[r], f2[r], f3[r]);
      cvalf[half][pos] = f4[r];
    }
  }
  __syncthreads();

  // scan: thread k walks its consecutive compacted range (ascending t)
  if (c < NCHUNK && lt < NK) {
    int n = cntS[half][lt];
    int base = offxS[half][lt] - n;
    float s0 = 0.f, s1 = 0.f, s2 = 0.f, s3 = 0.f, s4 = 0.f, s5 = 0.f;
    for (int m = 0; m < n; ++m) {
      float4 vv = cval4[half][base + m];
      float ww = cvalf[half][base + m];
      s0 = __fadd_rn(s0, vv.x);
      s1 = __fadd_rn(s1, vv.y);
      s2 = __fadd_rn(s2, vv.z);
      s3 = __fadd_rn(s3, vv.w);
      s4 = __fadd_rn(s4, ww);
      s5 += 1.0f;
    }
    // k-major layout [b][k][j][c]: combine reads contiguous
    float* pp = partials + ((size_t)(b * NK + lt) * 6) * NCHUNK + c;
    pp[0 * NCHUNK] = s0; pp[1 * NCHUNK] = s1; pp[2 * NCHUNK] = s2;
    pp[3 * NCHUNK] = s3; pp[4 * NCHUNK] = s4; pp[5 * NCHUNK] = s5;
  }
}

// ---------- combine: 8 bk-rows per block; LDS-staged 131-chains ----------
// Per-row op order identical to the original 1-row/block version (sequential
// adds chunk0..130; c2 chain sequential) => centers/c2 bit-identical.
__global__ void __launch_bounds__(256) combine_update_kernel(
    float* __restrict__ centers, const float* __restrict__ partials,
    float* __restrict__ c2g) {
  __shared__ float st[8 * 6 * NCHUNK];
  __shared__ float sums[8][6];
  __shared__ float newc[8][5];
  int bb = blockIdx.x;                 // handles bk in [bb*8, bb*8+8)
  int tid = threadIdx.x;
  const float* base = partials + (size_t)bb * 8 * 6 * NCHUNK;
  // 6288 floats = 1572 float4 (both pointers 16B-aligned)
  for (int t = tid; t < (8 * 6 * NCHUNK) / 4; t += 256)
    ((float4*)st)[t] = ((const float4*)base)[t];
  __syncthreads();
  if (tid < 48) {
    int row = tid / 6, comp = tid - 6 * (tid / 6);
    const float* rp = st + (row * 6 + comp) * NCHUNK;
    float s = rp[0];                   // C = 0 + chunk0 (exact)
    for (int c = 1; c < NCHUNK; ++c) s = __fadd_rn(s, rp[c]);
    sums[row][comp] = s;
  }
  __syncthreads();
  if (tid < 40) {
    int row = tid / 5, d = tid - 5 * (tid / 5);
    float cntv = sums[row][5];
    float* cc = centers + (size_t)(bb * 8 + row) * 5;
    float v;
    if (cntv > 0.0f) {                 // where(cnt>0, new, centers)
      float m = fmaxf(cntv, 1.0f);     // np.maximum(cnt,1.0): exact int in f32
      v = __fdiv_rn(sums[row][d], m);
      cc[d] = v;
    } else {
      v = cc[d];                       // unchanged center
    }
    newc[row][d] = v;
  }
  __syncthreads();
  if (tid < 8) {
    // c2 = sum(centers*centers): rounded products, sequential adds
    float t0 = __fmul_rn(newc[tid][0], newc[tid][0]);
    t0 = __fadd_rn(t0, __fmul_rn(newc[tid][1], newc[tid][1]));
    t0 = __fadd_rn(t0, __fmul_rn(newc[tid][2], newc[tid][2]));
    t0 = __fadd_rn(t0, __fmul_rn(newc[tid][3], newc[tid][3]));
    t0 = __fadd_rn(t0, __fmul_rn(newc[tid][4], newc[tid][4]));
    c2g[bb * 8 + tid] = t0;
  }
}

// ---------- embed (label fused in): block = (b, p, q-group-of-4) -----------
// The block labels its own 28-row x (<=70)-col strip: strip-box pruning
// (UB over the box's corners + 1.0 slack) gives a candidate SUPERSET of every
// pixel's argmin; walking candidates ascending-k with the identical dist5s
// sequence makes each pixel's label bit-identical to the full argmin — same
// proof as the per-window version, just a bigger box (~30 candidates).
// Label + accumulate in one pass; labels never touch global memory.
__global__ void __launch_bounds__(256) embed_kernel(
    const float* __restrict__ x, const float* __restrict__ centers,
    const float* __restrict__ c2g, const float* __restrict__ Ag,
    float* __restrict__ out) {
  __shared__ float Apv[28];
  __shared__ float Aqw[4][28];
  __shared__ float sk[4][NK * 3];
  __shared__ float4 ck4[NK];
  __shared__ float2 ck2[NK];
  __shared__ float ubk[128];
  __shared__ unsigned int candm[4];
  int b = blockIdx.y;
  int p = blockIdx.x >> 2;
  int qg = blockIdx.x & 3;
  int q0 = qg * 4;
  int tid = threadIdx.x;

  int h0 = max(0, 14 * p - 7), h1 = min(IMGD - 1, 14 * p + 20);
  int hl = h1 - h0 + 1;
  int w0q[4], w1q[4];
#pragma unroll
  for (int qi = 0; qi < 4; ++qi) {
    int q = q0 + qi;
    w0q[qi] = max(0, 14 * q - 7);
    w1q[qi] = min(IMGD - 1, 14 * q + 20);
  }
  int W0 = w0q[0], W1 = w1q[3];
  int WU = W1 - W0 + 1;

  const float* cb = centers + (size_t)b * NK * 5;
  const float* c2b = c2g + (size_t)b * NK;
  if (tid < NK) {
    ck4[tid] = make_float4(cb[tid*5+0], cb[tid*5+1], cb[tid*5+2], cb[tid*5+3]);
    ck2[tid] = make_float2(cb[tid*5+4], c2b[tid]);
  }
  if (tid < hl) Apv[tid] = Ag[p * IMGD + h0 + tid];
  {
    int t = tid - 64;
    if (t >= 0 && t < 112) {
      int qi = t / 28, dw = t - 28 * qi;
      if (dw <= w1q[qi] - w0q[qi])
        Aqw[qi][dw] = Ag[(q0 + qi) * IMGD + w0q[qi] + dw];
    }
  }
  for (int t = tid; t < 4 * NK * 3; t += 256)
    sk[t / (NK * 3)][t % (NK * 3)] = 0.0f;
  if (tid < 4) candm[tid] = 0u;
  __syncthreads();

  // strip-box pruning: UB = min_k(corner-max^2+3); keep iff clampdist^2<=UB+1
  const float ratio = ratio_f32();
  float f3mn = __fmul_rn((float)h0, ratio);
  float f3mx = __fmul_rn((float)h1, ratio);
  float f4mn = __fmul_rn((float)W0, ratio);
  float f4mx = __fmul_rn((float)W1, ratio);
  if (tid < 128) {
    float u = 3.4e38f;
    if (tid < NK) {
      float c3 = ck4[tid].w, c4 = ck2[tid].x;
      float dy = fmaxf(fabsf(c3 - f3mn), fabsf(c3 - f3mx));
      float dx = fmaxf(fabsf(c4 - f4mn), fabsf(c4 - f4mx));
      u = dy * dy + dx * dx + 3.0f;
    }
    ubk[tid] = u;
  }
  __syncthreads();
  for (int s = 64; s > 0; s >>= 1) {
    if (tid < s) ubk[tid] = fminf(ubk[tid], ubk[tid + s]);
    __syncthreads();
  }
  float lim = ubk[0] + 1.0f;
  if (tid < NK) {
    float c3 = ck4[tid].w, c4 = ck2[tid].x;
    float dy = fmaxf(0.0f, fmaxf(f3mn - c3, c3 - f3mx));
    float dx = fmaxf(0.0f, fmaxf(f4mn - c4, c4 - f4mx));
    if (dy * dy + dx * dx <= lim)
      atomicOr(&candm[tid >> 5], 1u << (tid & 31));
  }
  __syncthreads();

  // label + accumulate in one pass over the strip
  const float* xb = x + (size_t)b * 3 * HW;
  int n = hl * WU;                    // <= 28*70 = 1960 <= 8*256
  for (int r = 0; r < 8; ++r) {
    int idx = tid + r * 256;
    if (idx >= n) break;
    int dh = idx / WU;
    int dcol = idx - dh * WU;
    int col = W0 + dcol;
    int hh = h0 + dh;
    int i = hh * IMGD + col;
    float v0 = xb[i], v1 = xb[HW + i], v2 = xb[2 * HW + i];
    float f3 = __fmul_rn((float)hh, ratio);
    float f4 = __fmul_rn((float)col, ratio);
    float fq = fsq5(v0, v1, v2, f3, f4);
    float bestd = 3.4e38f; int bk = 0;
    for (int w = 0; w < 4; ++w) {     // ascending k: first-index ties safe
      unsigned int m = candm[w];
      while (m) {
        int j = __ffs(m) - 1;
        m &= m - 1;
        int k = (w << 5) + j;
        float4 a4 = ck4[k];
        float2 a2 = ck2[k];
        float d = dist5s(v0, v1, v2, f3, f4, fq,
                         a4.x, a4.y, a4.z, a4.w, a2.x, a2.y);
        if (d < bestd) { bestd = d; bk = k; }
      }
    }
    float ap = Apv[dh];
#pragma unroll
    for (int qi = 0; qi < 4; ++qi) {
      if (col >= w0q[qi] && col <= w1q[qi]) {
        float wgt = ap * Aqw[qi][col - w0q[qi]];
        atomicAdd(&sk[qi][bk * 3 + 0], wgt * v0);
        atomicAdd(&sk[qi][bk * 3 + 1], wgt * v1);
        atomicAdd(&sk[qi][bk * 3 + 2], wgt * v2);
      }
    }
  }
  __syncthreads();

  float* outb = out + (size_t)b * OUT_PER_B;
  for (int t = tid; t < 4 * NK * 3; t += 256) {
    int qi = t / (NK * 3), t3 = t - qi * (NK * 3);
    int k = t3 / 3, cc = t3 - 3 * k;
    int base = p * 48 + (q0 + qi) * 3;
    int f = k * 768 + base + cc;              // flat [K,P,P,C] index
    outb[(f & 255) * 300 + (f >> 8)] = sk[qi][t3]; // view(B,300,256)+transpose
  }
}

extern "C" void kernel_launch(void* const* d_in, const int* in_sizes, int n_in,
                              void* d_out, int out_size, void* d_ws, size_t ws_size,
                              hipStream_t stream) {
  const float* x = (const float*)d_in[0];
  float* out = (float*)d_out;
  char* ws = (char*)d_ws;
  // ws layout:
  float* centers  = (float*)(ws + 16384);      // 16000 B
  float* c2g      = (float*)(ws + 49152);      // 3200 B
  float* Ag       = (float*)(ws + 65536);      // 16*224*4 = 14336 B
  float* partials = (float*)(ws + 1703936);    // 8*100*6*131*4 = 2515200 B

  dim3 ig0(67, NB);               // bx 0..65: chunk pairs; bx 66: A-setup
  dim3 ig(66, NB);                // 528 blocks
  iter_kernel<<<ig0, 256, 0, stream>>>(x, centers, c2g, partials, 0, Ag);
  combine_update_kernel<<<NB * NK / 8, 256, 0, stream>>>(centers, partials, c2g);
  for (int it = 1; it < 10; ++it) {
    iter_kernel<<<ig, 256, 0, stream>>>(x, centers, c2g, partials, 1, Ag);
    combine_update_kernel<<<NB * NK / 8, 256, 0, stream>>>(centers, partials, c2g);
  }
  dim3 egrid(64, NB);             // (p*4 + qgroup) x b — 512 blocks
  embed_kernel<<<egrid, 256, 0, stream>>>(x, centers, c2g, Ag, out);
}

// Round 5
// 291.698 us; speedup vs baseline: 11.1382x; 1.0590x over previous
//
#include <hip/hip_runtime.h>
#include <math.h>

#define IMGD 224
#define HW 50176      // 224*224
#define NK 100
#define NB 8
#define OUT_PER_B 76800   // 100*16*16*3 = 300*256
#define NCHUNK 131        // chunking of 50176: 129x384 + 2x320
#define MSTR 13           // mask/ppk row stride (13 coprime 32: no bank conflicts)

// Session ledger:
// - Cross-block coherence inside a kernel: DEAD (grid.sync ~146us, R3).
// - Per-workgroup ramp: DEAD (R2 null). Fixed ~13us/boundary: DEAD (R4:
//   removing 2 boundaries saved ~8us => boundary ~4us).
// - Label-in-embed fusion: DEAD (+21us strip candidates > boundary savings).
// - LIVE theory (this round): iter grid 528 > guaranteed residency 512
//   (launch_bounds(256,2)) => 16-block tail doubles iter wall time. Fix:
//   launch_bounds(256,4) (LDS 37.4KB -> 4 blocks/CU, capacity 1024).

static __device__ __forceinline__ float ratio_f32() {
  return (float)(10.0 / sqrt(224.0 * 224.0 / 100.0));
}

// distance op sequence — the single source of truth for bit-exactness
static __device__ __forceinline__ float dist5s(float f0, float f1, float f2,
                                               float f3, float f4, float fsq,
                                               float c0, float c1, float c2,
                                               float c3, float c4, float q) {
  float dot = __fmul_rn(f0, c0);
  dot = __fmaf_rn(f1, c1, dot);
  dot = __fmaf_rn(f2, c2, dot);
  dot = __fmaf_rn(f3, c3, dot);
  dot = __fmaf_rn(f4, c4, dot);
  return __fsub_rn(__fadd_rn(fsq, q), __fmul_rn(2.0f, dot));
}

static __device__ __forceinline__ float fsq5(float f0, float f1, float f2,
                                             float f3, float f4) {
  float s = __fmul_rn(f0, f0);
  s = __fadd_rn(s, __fmul_rn(f1, f1));
  s = __fadd_rn(s, __fmul_rn(f2, f2));
  s = __fadd_rn(s, __fmul_rn(f3, f3));
  s = __fadd_rn(s, __fmul_rn(f4, f4));
  return s;
}

// ---------- fused assign+partial: 2 chunks per 256-thread block ----------
// half = tid>>7 picks chunk c = 2*bx + half; lt = tid&127 runs the per-chunk
// code with chunk-local LDS indexed [half]. Centers shared (same b).
// bx==66 blocks (flag==0 grid only) materialize resize-matrix rows 2b,2b+1
// into Ag (identical 128-wide tree pairing => A bit-identical).
// Pruning: UB = min_k(dy_max^2+dx_max^2+3), keep k iff dy_min^2+dx_min^2 <=
// UB+1.0 (slack >> f32 rounding); candidates walked ascending-k straight out
// of the candm bitmask => argmin + first-index ties bit-preserved.
__global__ void __launch_bounds__(256, 4) iter_kernel(
    const float* __restrict__ x, float* __restrict__ centers,
    const float* __restrict__ c2g, float* __restrict__ partials, int flag,
    float* __restrict__ Ag) {
  __shared__ float4 ck4[NK];
  __shared__ float2 ck2[NK];
  __shared__ unsigned int maskS[2][NK * MSTR];
  __shared__ unsigned short ppkS[2][NK * MSTR];
  __shared__ float4 cval4[2][384];
  __shared__ float  cvalf[2][384];
  __shared__ int cntS[2][128];
  __shared__ int offxS[2][128];
  __shared__ int wtotS[2];
  __shared__ float ubpart[2][12][10];
  __shared__ float ubg[2][12];
  __shared__ unsigned int candm[2][12][4];
  __shared__ float ared[128];
  int bx = blockIdx.x, b = blockIdx.y;
  int tid = threadIdx.x;

  if (bx >= 66) {
    // ---- A-setup block (present only in the flag==0 dispatch) ----
    for (int rr = 0; rr < 2; ++rr) {
      int p = 2 * b + rr;
      float cp = (p + 0.5f) * 14.0f - 0.5f;
      if (tid < 128) {
        // level s=128 of the old 256-wide tree: red[t] = tri(t) + tri(t+128)
        float xd0 = fabsf(cp - (float)tid) / 14.0f;
        float trip0 = fmaxf(0.0f, 1.0f - xd0);
        float trip1 = 0.0f;
        int t2 = tid + 128;
        if (t2 < IMGD) {
          float xd = fabsf(cp - (float)t2) / 14.0f;
          trip1 = fmaxf(0.0f, 1.0f - xd);
        }
        ared[tid] = trip0 + trip1;
      }
      __syncthreads();
      for (int s = 64; s > 0; s >>= 1) {
        if (tid < s) ared[tid] += ared[tid + s];
        __syncthreads();
      }
      float Zp = ared[0];
      __syncthreads();
      if (tid < IMGD) {
        float xd = fabsf(cp - (float)tid) / 14.0f;
        Ag[p * IMGD + tid] = fmaxf(0.0f, 1.0f - xd) / Zp;  // same expr as before
      }
      __syncthreads();
    }
    return;
  }

  int half = tid >> 7;
  int lt = tid & 127;
  int c = 2 * bx + half;
  int start, len;
  if (c < NCHUNK) {
    start = (c < 129) ? c * 384 : 49536 + (c - 129) * 320;
    len   = (c < 129) ? 384 : 320;
  } else {
    start = 0; len = 0;                 // bx==65 half1: inert chunk
  }

  const float ratio = ratio_f32();
  const float* x0 = x + (size_t)b * 3 * HW;
  if (flag == 0) {
    // self-init: same ops as the original setup => identical center values
    if (tid < NK) {
      int gy = tid / 10, gx = tid - 10 * (tid / 10);
      int cy = (int)((gy + 0.5) * 224.0 / 10.0);  // trunc like .astype(int32)
      int cx = (int)((gx + 0.5) * 224.0 / 10.0);
      int i = cy * IMGD + cx;
      float c0 = x0[i], c1 = x0[HW + i], c2 = x0[2 * HW + i];
      float c3 = __fmul_rn((float)cy, ratio);
      float c4 = __fmul_rn((float)cx, ratio);
      float s = __fmul_rn(c0, c0);
      s = __fadd_rn(s, __fmul_rn(c1, c1));
      s = __fadd_rn(s, __fmul_rn(c2, c2));
      s = __fadd_rn(s, __fmul_rn(c3, c3));
      s = __fadd_rn(s, __fmul_rn(c4, c4));
      ck4[tid] = make_float4(c0, c1, c2, c3);
      ck2[tid] = make_float2(c4, s);
      if (bx == 0) {   // persist for combine#1's cnt==0 carryover
        float* oc = centers + ((size_t)b * NK + tid) * 5;
        oc[0] = c0; oc[1] = c1; oc[2] = c2; oc[3] = c3; oc[4] = c4;
      }
    }
  } else {
    const float* cb = centers + (size_t)b * NK * 5;
    const float* c2b = c2g + (size_t)b * NK;
    if (tid < NK) {
      ck4[tid] = make_float4(cb[tid*5+0], cb[tid*5+1], cb[tid*5+2], cb[tid*5+3]);
      ck2[tid] = make_float2(cb[tid*5+4], c2b[tid]);
    }
  }
  for (int t = lt; t < NK * MSTR; t += 128) maskS[half][t] = 0u;
  if (lt < 48) candm[half][lt >> 2][lt & 3] = 0u;

  // pixel loads early (no LDS dependence) — overlap with pruning phases
  float f0[3], f1[3], f2[3], f3[3], f4[3], fq[3];
  bool vld[3];
  for (int r = 0; r < 3; ++r) {
    int t = lt + r * 128;
    vld[r] = (t < len);
    int i = start + (vld[r] ? t : 0);
    int y = i / IMGD, xw = i - y * IMGD;
    f0[r] = x0[i]; f1[r] = x0[HW + i]; f2[r] = x0[2 * HW + i];
    f3[r] = __fmul_rn((float)y, ratio);
    f4[r] = __fmul_rn((float)xw, ratio);
    fq[r] = fsq5(f0[r], f1[r], f2[r], f3[r], f4[r]);
  }
  __syncthreads();

  // UB phase: thread (g,kb) scans 10 centers; group bounds in-register
  if (lt < 120) {
    int g = lt / 10, kb = lt - 10 * g;
    int i0 = start + g * 32, i1 = i0 + 31;
    int ymin = i0 / IMGD, ymax = i1 / IMGD;
    int cmin = (ymin == ymax) ? (i0 - ymin * IMGD) : 0;
    int cmax = (ymin == ymax) ? (i1 - ymax * IMGD) : (IMGD - 1);
    float f3mn = __fmul_rn((float)ymin, ratio);
    float f3mx = __fmul_rn((float)ymax, ratio);
    float f4mn = __fmul_rn((float)cmin, ratio);
    float f4mx = __fmul_rn((float)cmax, ratio);
    float mn = 3.4e38f;
    for (int k = kb * 10; k < kb * 10 + 10; ++k) {
      float c3 = ck4[k].w, c4 = ck2[k].x;
      float dy = fmaxf(fabsf(c3 - f3mn), fabsf(c3 - f3mx));
      float dx = fmaxf(fabsf(c4 - f4mn), fabsf(c4 - f4mx));
      mn = fminf(mn, dy * dy + dx * dx + 3.0f);
    }
    ubpart[half][g][kb] = mn;
  }
  __syncthreads();
  if (lt < 12) {
    float mn = ubpart[half][lt][0];
    for (int j = 1; j < 10; ++j) mn = fminf(mn, ubpart[half][lt][j]);
    ubg[half][lt] = mn + 1.0f;  // slack >> all f32 rounding at these magnitudes
  }
  __syncthreads();
  if (lt < 120) {
    int g = lt / 10, kb = lt - 10 * g;
    int i0 = start + g * 32, i1 = i0 + 31;
    int ymin = i0 / IMGD, ymax = i1 / IMGD;
    int cmin = (ymin == ymax) ? (i0 - ymin * IMGD) : 0;
    int cmax = (ymin == ymax) ? (i1 - ymax * IMGD) : (IMGD - 1);
    float f3mn = __fmul_rn((float)ymin, ratio);
    float f3mx = __fmul_rn((float)ymax, ratio);
    float f4mn = __fmul_rn((float)cmin, ratio);
    float f4mx = __fmul_rn((float)cmax, ratio);
    float lim = ubg[half][g];
    for (int k = kb * 10; k < kb * 10 + 10; ++k) {
      float c3 = ck4[k].w, c4 = ck2[k].x;
      float dy = fmaxf(0.0f, fmaxf(f3mn - c3, c3 - f3mx));
      float dx = fmaxf(0.0f, fmaxf(f4mn - c4, c4 - f4mx));
      if (dy * dy + dx * dx <= lim)
        atomicOr(&candm[half][g][k >> 5], 1u << (k & 31));
    }
  }
  __syncthreads();

  // pruned distance loop straight off the candm bitmask: k ascending
  // (w asc, ffs asc) — identical candidate sequence to the dense-list
  // version; first-index ties preserved.
  float best[3]; int bk[3];
  for (int r = 0; r < 3; ++r) {
    best[r] = 3.4e38f; bk[r] = 0;
    int t = lt + r * 128;
    int g = (t < 384) ? (t >> 5) : 0;
    for (int w = 0; w < 4; ++w) {
      unsigned int m = candm[half][g][w];
      while (m) {
        int j = __ffs(m) - 1;
        m &= m - 1;
        int k = (w << 5) + j;
        float4 a4 = ck4[k];
        float2 a2 = ck2[k];
        float d = dist5s(f0[r], f1[r], f2[r], f3[r], f4[r], fq[r],
                         a4.x, a4.y, a4.z, a4.w, a2.x, a2.y);
        if (d < best[r]) { best[r] = d; bk[r] = k; }
      }
    }
  }
  for (int r = 0; r < 3; ++r) {
    int t = lt + r * 128;
    if (vld[r]) atomicOr(&maskS[half][bk[r] * MSTR + (t >> 5)], 1u << (t & 31));
  }
  __syncthreads();

  // per-k cumulative popcounts (stride-13 rows: conflict-free)
  int myCnt = 0;
  if (lt < NK) {
    int s = 0;
    for (int g = 0; g < 12; ++g) {
      ppkS[half][lt * MSTR + g] = (unsigned short)s;
      s += __popc(maskS[half][lt * MSTR + g]);
    }
    myCnt = s;
  }
  cntS[half][lt] = myCnt;
  __syncthreads();

  // inclusive prefix over 128 counts per half: shfl per wave + cross-wave fixup
  int v = myCnt;
  for (int d = 1; d < 64; d <<= 1) {
    int u = __shfl_up(v, d, 64);
    if ((tid & 63) >= d) v += u;
  }
  if (lt == 63) wtotS[half] = v;
  __syncthreads();
  if (lt >= 64) v += wtotS[half];
  offxS[half][lt] = v;
  __syncthreads();

  // stable VALUE scatter: pos = (off[k]-cnt[k]) + rank_within_k(t)
  for (int r = 0; r < 3; ++r) {
    int t = lt + r * 128;
    if (vld[r]) {
      int g = t >> 5, j = t & 31;
      unsigned int m = maskS[half][bk[r] * MSTR + g];
      int rank = ppkS[half][bk[r] * MSTR + g] + __popc(m & ((1u << j) - 1u));
      int pos = offxS[half][bk[r]] - cntS[half][bk[r]] + rank;
      cval4[half][pos] = make_float4(f0[r], f1[r], f2[r], f3[r]);
      cvalf[half][pos] = f4[r];
    }
  }
  __syncthreads();

  // scan: thread k walks its consecutive compacted range (ascending t)
  if (c < NCHUNK && lt < NK) {
    int n = cntS[half][lt];
    int base = offxS[half][lt] - n;
    float s0 = 0.f, s1 = 0.f, s2 = 0.f, s3 = 0.f, s4 = 0.f, s5 = 0.f;
    for (int m = 0; m < n; ++m) {
      float4 vv = cval4[half][base + m];
      float ww = cvalf[half][base + m];
      s0 = __fadd_rn(s0, vv.x);
      s1 = __fadd_rn(s1, vv.y);
      s2 = __fadd_rn(s2, vv.z);
      s3 = __fadd_rn(s3, vv.w);
      s4 = __fadd_rn(s4, ww);
      s5 += 1.0f;
    }
    // k-major layout [b][k][j][c]: combine reads contiguous
    float* pp = partials + ((size_t)(b * NK + lt) * 6) * NCHUNK + c;
    pp[0 * NCHUNK] = s0; pp[1 * NCHUNK] = s1; pp[2 * NCHUNK] = s2;
    pp[3 * NCHUNK] = s3; pp[4 * NCHUNK] = s4; pp[5 * NCHUNK] = s5;
  }
}

// ---------- combine: 8 bk-rows per block; LDS-staged 131-chains ----------
// Per-row op order identical to the original 1-row/block version (sequential
// adds chunk0..130; c2 chain sequential) => centers/c2 bit-identical.
__global__ void __launch_bounds__(256) combine_update_kernel(
    float* __restrict__ centers, const float* __restrict__ partials,
    float* __restrict__ c2g) {
  __shared__ float st[8 * 6 * NCHUNK];
  __shared__ float sums[8][6];
  __shared__ float newc[8][5];
  int bb = blockIdx.x;                 // handles bk in [bb*8, bb*8+8)
  int tid = threadIdx.x;
  const float* base = partials + (size_t)bb * 8 * 6 * NCHUNK;
  // 6288 floats = 1572 float4 (both pointers 16B-aligned)
  for (int t = tid; t < (8 * 6 * NCHUNK) / 4; t += 256)
    ((float4*)st)[t] = ((const float4*)base)[t];
  __syncthreads();
  if (tid < 48) {
    int row = tid / 6, comp = tid - 6 * (tid / 6);
    const float* rp = st + (row * 6 + comp) * NCHUNK;
    float s = rp[0];                   // C = 0 + chunk0 (exact)
    for (int c = 1; c < NCHUNK; ++c) s = __fadd_rn(s, rp[c]);
    sums[row][comp] = s;
  }
  __syncthreads();
  if (tid < 40) {
    int row = tid / 5, d = tid - 5 * (tid / 5);
    float cntv = sums[row][5];
    float* cc = centers + (size_t)(bb * 8 + row) * 5;
    float v;
    if (cntv > 0.0f) {                 // where(cnt>0, new, centers)
      float m = fmaxf(cntv, 1.0f);     // np.maximum(cnt,1.0): exact int in f32
      v = __fdiv_rn(sums[row][d], m);
      cc[d] = v;
    } else {
      v = cc[d];                       // unchanged center
    }
    newc[row][d] = v;
  }
  __syncthreads();
  if (tid < 8) {
    // c2 = sum(centers*centers): rounded products, sequential adds
    float t0 = __fmul_rn(newc[tid][0], newc[tid][0]);
    t0 = __fadd_rn(t0, __fmul_rn(newc[tid][1], newc[tid][1]));
    t0 = __fadd_rn(t0, __fmul_rn(newc[tid][2], newc[tid][2]));
    t0 = __fadd_rn(t0, __fmul_rn(newc[tid][3], newc[tid][3]));
    t0 = __fadd_rn(t0, __fmul_rn(newc[tid][4], newc[tid][4]));
    c2g[bb * 8 + tid] = t0;
  }
}

// ---------- labels: final assignment w.r.t. centers_10, written ONCE ----------
// Front half of iter_kernel (identical loads, identical pruning bound,
// identical dist5s op sequence, candidates ascending-k from the candm
// bitmask) => labels bit-identical to the full argmin.
__global__ void __launch_bounds__(128, 4) label_kernel(
    const float* __restrict__ x, const float* __restrict__ centers,
    const float* __restrict__ c2g, unsigned char* __restrict__ labels) {
  __shared__ float4 ck4[NK];
  __shared__ float2 ck2[NK];
  __shared__ float ubpart[12][10];
  __shared__ float ubg[12];
  __shared__ unsigned int candm[12][4];
  int c = blockIdx.x, b = blockIdx.y;
  int tid = threadIdx.x;
  int start = (c < 129) ? c * 384 : 49536 + (c - 129) * 320;
  int len   = (c < 129) ? 384 : 320;

  const float ratio = ratio_f32();
  const float* x0 = x + (size_t)b * 3 * HW;
  const float* cb = centers + (size_t)b * NK * 5;
  const float* c2b = c2g + (size_t)b * NK;
  if (tid < NK) {
    ck4[tid] = make_float4(cb[tid*5+0], cb[tid*5+1], cb[tid*5+2], cb[tid*5+3]);
    ck2[tid] = make_float2(cb[tid*5+4], c2b[tid]);
  }
  if (tid < 48) candm[tid >> 2][tid & 3] = 0u;

  float f0[3], f1[3], f2[3], f3[3], f4[3], fq[3];
  int ii[3];
  bool vld[3];
  for (int r = 0; r < 3; ++r) {
    int t = tid + r * 128;
    vld[r] = (t < len);
    int i = start + (vld[r] ? t : 0);
    ii[r] = i;
    int y = i / IMGD, xw = i - y * IMGD;
    f0[r] = x0[i]; f1[r] = x0[HW + i]; f2[r] = x0[2 * HW + i];
    f3[r] = __fmul_rn((float)y, ratio);
    f4[r] = __fmul_rn((float)xw, ratio);
    fq[r] = fsq5(f0[r], f1[r], f2[r], f3[r], f4[r]);
  }
  __syncthreads();

  if (tid < 120) {
    int g = tid / 10, kb = tid - 10 * g;
    int i0 = start + g * 32, i1 = i0 + 31;
    int ymin = i0 / IMGD, ymax = i1 / IMGD;
    int cmin = (ymin == ymax) ? (i0 - ymin * IMGD) : 0;
    int cmax = (ymin == ymax) ? (i1 - ymax * IMGD) : (IMGD - 1);
    float f3mn = __fmul_rn((float)ymin, ratio);
    float f3mx = __fmul_rn((float)ymax, ratio);
    float f4mn = __fmul_rn((float)cmin, ratio);
    float f4mx = __fmul_rn((float)cmax, ratio);
    float mn = 3.4e38f;
    for (int k = kb * 10; k < kb * 10 + 10; ++k) {
      float c3 = ck4[k].w, c4 = ck2[k].x;
      float dy = fmaxf(fabsf(c3 - f3mn), fabsf(c3 - f3mx));
      float dx = fmaxf(fabsf(c4 - f4mn), fabsf(c4 - f4mx));
      mn = fminf(mn, dy * dy + dx * dx + 3.0f);
    }
    ubpart[g][kb] = mn;
  }
  __syncthreads();
  if (tid < 12) {
    float mn = ubpart[tid][0];
    for (int j = 1; j < 10; ++j) mn = fminf(mn, ubpart[tid][j]);
    ubg[tid] = mn + 1.0f;
  }
  __syncthreads();
  if (tid < 120) {
    int g = tid / 10, kb = tid - 10 * g;
    int i0 = start + g * 32, i1 = i0 + 31;
    int ymin = i0 / IMGD, ymax = i1 / IMGD;
    int cmin = (ymin == ymax) ? (i0 - ymin * IMGD) : 0;
    int cmax = (ymin == ymax) ? (i1 - ymax * IMGD) : (IMGD - 1);
    float f3mn = __fmul_rn((float)ymin, ratio);
    float f3mx = __fmul_rn((float)ymax, ratio);
    float f4mn = __fmul_rn((float)cmin, ratio);
    float f4mx = __fmul_rn((float)cmax, ratio);
    float lim = ubg[g];
    for (int k = kb * 10; k < kb * 10 + 10; ++k) {
      float c3 = ck4[k].w, c4 = ck2[k].x;
      float dy = fmaxf(0.0f, fmaxf(f3mn - c3, c3 - f3mx));
      float dx = fmaxf(0.0f, fmaxf(f4mn - c4, c4 - f4mx));
      if (dy * dy + dx * dx <= lim)
        atomicOr(&candm[g][k >> 5], 1u << (k & 31));
    }
  }
  __syncthreads();

  float best[3]; int bk[3];
  for (int r = 0; r < 3; ++r) {
    best[r] = 3.4e38f; bk[r] = 0;
    int t = tid + r * 128;
    int g = (t < 384) ? (t >> 5) : 0;
    for (int w = 0; w < 4; ++w) {
      unsigned int m = candm[g][w];
      while (m) {
        int j = __ffs(m) - 1;
        m &= m - 1;
        int k = (w << 5) + j;
        float4 a4 = ck4[k];
        float2 a2 = ck2[k];
        float d = dist5s(f0[r], f1[r], f2[r], f3[r], f4[r], fq[r],
                         a4.x, a4.y, a4.z, a4.w, a2.x, a2.y);
        if (d < best[r]) { best[r] = d; bk[r] = k; }
      }
    }
  }
  unsigned char* lb = labels + (size_t)b * HW;
  for (int r = 0; r < 3; ++r)
    if (vld[r]) lb[ii[r]] = (unsigned char)bk[r];
}

// ---------- embed: block = (b, p, q-group-of-4); A + labels precomputed ----
// One block covers 4 q-windows sharing rows h0..h1: pixels in the union col
// range loaded once, scattered into up to 2 overlapping windows' LDS bins.
__global__ void __launch_bounds__(256) embed_kernel(
    const float* __restrict__ x, const unsigned char* __restrict__ labels,
    const float* __restrict__ Ag, float* __restrict__ out) {
  __shared__ float Apv[28];
  __shared__ float Aqw[4][28];
  __shared__ float sk[4][NK * 3];
  int b = blockIdx.y;
  int p = blockIdx.x >> 2;
  int qg = blockIdx.x & 3;
  int q0 = qg * 4;
  int tid = threadIdx.x;

  int h0 = max(0, 14 * p - 7), h1 = min(IMGD - 1, 14 * p + 20);
  int hl = h1 - h0 + 1;
  int w0q[4], w1q[4];
#pragma unroll
  for (int qi = 0; qi < 4; ++qi) {
    int q = q0 + qi;
    w0q[qi] = max(0, 14 * q - 7);
    w1q[qi] = min(IMGD - 1, 14 * q + 20);
  }
  int W0 = w0q[0], W1 = w1q[3];
  int WU = W1 - W0 + 1;

  if (tid < hl) Apv[tid] = Ag[p * IMGD + h0 + tid];
  {
    int t = tid - 64;
    if (t >= 0 && t < 112) {
      int qi = t / 28, dw = t - 28 * qi;
      if (dw <= w1q[qi] - w0q[qi])
        Aqw[qi][dw] = Ag[(q0 + qi) * IMGD + w0q[qi] + dw];
    }
  }
  for (int t = tid; t < 4 * NK * 3; t += 256)
    sk[t / (NK * 3)][t % (NK * 3)] = 0.0f;
  __syncthreads();

  const float* xb = x + (size_t)b * 3 * HW;
  const unsigned char* lb = labels + (size_t)b * HW;
  int n = hl * WU;                    // <= 28*70 = 1960 <= 8*256
  for (int r = 0; r < 8; ++r) {
    int idx = tid + r * 256;
    if (idx >= n) break;
    int dh = idx / WU;
    int dcol = idx - dh * WU;
    int col = W0 + dcol;
    int i = (h0 + dh) * IMGD + col;
    float v0 = xb[i], v1 = xb[HW + i], v2 = xb[2 * HW + i];
    int k = lb[i];
    float ap = Apv[dh];
#pragma unroll
    for (int qi = 0; qi < 4; ++qi) {
      if (col >= w0q[qi] && col <= w1q[qi]) {
        float wgt = ap * Aqw[qi][col - w0q[qi]];
        atomicAdd(&sk[qi][k * 3 + 0], wgt * v0);
        atomicAdd(&sk[qi][k * 3 + 1], wgt * v1);
        atomicAdd(&sk[qi][k * 3 + 2], wgt * v2);
      }
    }
  }
  __syncthreads();

  float* outb = out + (size_t)b * OUT_PER_B;
  for (int t = tid; t < 4 * NK * 3; t += 256) {
    int qi = t / (NK * 3), t3 = t - qi * (NK * 3);
    int k = t3 / 3, cc = t3 - 3 * k;
    int base = p * 48 + (q0 + qi) * 3;
    int f = k * 768 + base + cc;              // flat [K,P,P,C] index
    outb[(f & 255) * 300 + (f >> 8)] = sk[qi][t3]; // view(B,300,256)+transpose
  }
}

extern "C" void kernel_launch(void* const* d_in, const int* in_sizes, int n_in,
                              void* d_out, int out_size, void* d_ws, size_t ws_size,
                              hipStream_t stream) {
  const float* x = (const float*)d_in[0];
  float* out = (float*)d_out;
  char* ws = (char*)d_ws;
  // ws layout:
  float* centers        = (float*)(ws + 16384);      // 16000 B
  float* c2g            = (float*)(ws + 49152);      // 3200 B
  float* Ag             = (float*)(ws + 65536);      // 16*224*4 = 14336 B
  unsigned char* labels = (unsigned char*)(ws + 98304); // 8*50176 = 401408 B
  float* partials       = (float*)(ws + 1703936);    // 8*100*6*131*4 = 2515200 B

  dim3 ig0(67, NB);               // bx 0..65: chunk pairs; bx 66: A-setup
  dim3 ig(66, NB);                // 528 blocks — all resident at 4 blocks/CU
  iter_kernel<<<ig0, 256, 0, stream>>>(x, centers, c2g, partials, 0, Ag);
  combine_update_kernel<<<NB * NK / 8, 256, 0, stream>>>(centers, partials, c2g);
  for (int it = 1; it < 10; ++it) {
    iter_kernel<<<ig, 256, 0, stream>>>(x, centers, c2g, partials, 1, Ag);
    combine_update_kernel<<<NB * NK / 8, 256, 0, stream>>>(centers, partials, c2g);
  }
  label_kernel<<<dim3(NCHUNK, NB), 128, 0, stream>>>(x, centers, c2g, labels);
  dim3 egrid(64, NB);             // (p*4 + qgroup) x b — 512 blocks
  embed_kernel<<<egrid, 256, 0, stream>>>(x, labels, Ag, out);
}